// Round 10
// baseline (180.098 us; speedup 1.0000x reference)
//
#include <hip/hip_runtime.h>
#include <hip/hip_fp16.h>
#include <math.h>

#define HEADS 8
#define DIM 32
#define NEG_SLOPE 0.2f

typedef float f32x2 __attribute__((ext_vector_type(2)));

__device__ inline float2 u2f2(unsigned int u) {
    __half2 h = __builtin_bit_cast(__half2, u);
    return __half22float2(h);
}

// Prep (merged): blocks [0, nb_logits): one wave per node — logits el/er into
// TRANSPOSED per-head tables el_ph/er_ph[h][node], and fp16 feat into
// per-head chunks feat_ph[h][node][32] (64 B per (h,node)).
// Blocks [nb_logits, ...): CSR rowptr from sorted dst_idx (edge-parallel).
__global__ __launch_bounds__(256) void gat_prep_kernel(
    const float4* __restrict__ feat4,    // node row = 64 float4
    const float4* __restrict__ attn_l4,  // 64 float4 (8 heads x 8)
    const float4* __restrict__ attn_r4,
    float* __restrict__ el_ph,           // [8][n_nodes]
    float* __restrict__ er_ph,           // [8][n_nodes]
    uint2* __restrict__ feat_ph2,        // [8][n_nodes][8] uint2 (=64B chunks)
    const int* __restrict__ dst,
    int* __restrict__ rowptr,
    int n_nodes, int n_edges, int nb_logits) {
    int b = blockIdx.x;
    if (b < nb_logits) {
        int wid = (b * 256 + threadIdx.x) >> 6;
        if (wid >= n_nodes) return;
        int lane = threadIdx.x & 63;
        int h = lane >> 3;
        int q = lane & 7;

        float4 al = attn_l4[lane];
        float4 ar = attn_r4[lane];
        float4 v  = feat4[(size_t)wid * 64 + lane];

        float sl = v.x * al.x + v.y * al.y + v.z * al.z + v.w * al.w;
        float sr = v.x * ar.x + v.y * ar.y + v.z * ar.z + v.w * ar.w;
#pragma unroll
        for (int off = 1; off < 8; off <<= 1) {
            sl += __shfl_xor(sl, off, 64);
            sr += __shfl_xor(sr, off, 64);
        }
        unsigned hN = (unsigned)h * (unsigned)n_nodes;
        if (q == 0) {
            el_ph[hN + wid] = sl;
            er_ph[hN + wid] = sr;
        }
        uint2 o;
        o.x = __builtin_bit_cast(unsigned int, __floats2half2_rn(v.x, v.y));
        o.y = __builtin_bit_cast(unsigned int, __floats2half2_rn(v.z, v.w));
        feat_ph2[((size_t)hN + (unsigned)wid) * 8 + q] = o;
    } else {
        int e = (b - nb_logits) * 256 + threadIdx.x;
        if (e >= n_edges) return;
        int d = dst[e];
        int prev = (e > 0) ? dst[e - 1] : -1;
        for (int v = prev + 1; v <= d; ++v) rowptr[v] = e;
        if (e == n_edges - 1) {
            for (int v = d + 1; v <= n_nodes; ++v) rowptr[v] = n_edges;
        }
    }
}

// Aggregate: head h = blockIdx.x & 7  -> under round-robin dispatch all
// blocks of head h land on XCD h, so each XCD's gather working set is its
// private 3.2 MB feat chunk + 200 KB el table (L2-resident, fetched once).
// One wave per (v,h): 4 edge-slots x 16 lanes x uint (2 halfs); unroll x2
// -> 8 edges in flight; shfl_xor(16,32) cross-slot reduction.
// src_idx / out accessed non-temporally (streaming, no reuse on this XCD).
// No max subtraction (|s| <~ 45 fits f32; softmax ratio identical).
__global__ __launch_bounds__(256) void gat_aggregate_kernel(
    const unsigned int* __restrict__ feat_ph,  // [8][n_nodes][16] uint
    const float* __restrict__ el_ph,           // [8][n_nodes]
    const float* __restrict__ er_ph,           // [8][n_nodes]
    const int* __restrict__ src_idx,
    const int* __restrict__ rowptr,
    f32x2* __restrict__ out2,                  // out as f32x2[n_nodes*128]
    int n_nodes) {
    int b = blockIdx.x;
    int h = b & 7;                      // XCD-partitioned head
    int vraw = (b >> 3) * 4 + (threadIdx.x >> 6);
    if (vraw >= n_nodes) return;
    int v = __builtin_amdgcn_readfirstlane(vraw);
    int lane = threadIdx.x & 63;
    int grp = lane >> 4;                // edge slot 0..3
    int ql  = lane & 15;                // dim-pair 0..15

    int start = __builtin_amdgcn_readfirstlane(rowptr[v]);
    int end   = __builtin_amdgcn_readfirstlane(rowptr[v + 1]);

    unsigned ob = ((unsigned)v << 7) + ((unsigned)h << 4) + (unsigned)ql;
    if (start == end) {
        if (grp == 0) {
            f32x2 z; z.x = 0.f; z.y = 0.f;
            __builtin_nontemporal_store(z, &out2[ob]);
        }
        return;
    }
    int endm1 = end - 1;
    unsigned hN = (unsigned)h * (unsigned)n_nodes;
    float er_vh = er_ph[hN + (unsigned)v];

    float accx0 = 0.f, accy0 = 0.f, den0 = 0.f;
    float accx1 = 0.f, accy1 = 0.f, den1 = 0.f;

    for (int e0 = start; e0 < end; e0 += 8) {
        int eA = e0 + grp;
        int eB = e0 + 4 + grp;
        int eeA = eA < endm1 ? eA : endm1;
        int eeB = eB < endm1 ? eB : endm1;
        int uA = __builtin_nontemporal_load(&src_idx[eeA]);
        int uB = __builtin_nontemporal_load(&src_idx[eeB]);
        unsigned int fA = feat_ph[((size_t)hN + (unsigned)uA) * 16 + ql];
        unsigned int fB = feat_ph[((size_t)hN + (unsigned)uB) * 16 + ql];
        float elA = el_ph[hN + (unsigned)uA];
        float elB = el_ph[hN + (unsigned)uB];
        float sA = elA + er_vh; sA = fmaxf(sA, NEG_SLOPE * sA);
        float sB = elB + er_vh; sB = fmaxf(sB, NEG_SLOPE * sB);
        if (eA > endm1) sA = -INFINITY;
        if (eB > endm1) sB = -INFINITY;
        float wA = __expf(sA);
        float wB = __expf(sB);
        float2 pA = u2f2(fA);
        float2 pB = u2f2(fB);
        den0 += wA; den1 += wB;
        accx0 += wA * pA.x; accy0 += wA * pA.y;
        accx1 += wB * pB.x; accy1 += wB * pB.y;
    }
    float accx = accx0 + accx1;
    float accy = accy0 + accy1;
    float den  = den0 + den1;
    accx += __shfl_xor(accx, 16, 64);
    accy += __shfl_xor(accy, 16, 64);
    den  += __shfl_xor(den,  16, 64);
    accx += __shfl_xor(accx, 32, 64);
    accy += __shfl_xor(accy, 32, 64);
    den  += __shfl_xor(den,  32, 64);
    if (grp == 0) {
        float inv = 1.f / den;
        f32x2 r; r.x = accx * inv; r.y = accy * inv;
        __builtin_nontemporal_store(r, &out2[ob]);
    }
}

extern "C" void kernel_launch(void* const* d_in, const int* in_sizes, int n_in,
                              void* d_out, int out_size, void* d_ws, size_t ws_size,
                              hipStream_t stream) {
    const float* feat   = (const float*)d_in[0];
    const float* attn_l = (const float*)d_in[1];
    const float* attn_r = (const float*)d_in[2];
    const int*   src    = (const int*)d_in[3];
    const int*   dst    = (const int*)d_in[4];
    float* out = (float*)d_out;

    int n_edges = in_sizes[3];
    int n_nodes = out_size / (HEADS * DIM);
    int nh = n_nodes * HEADS;

    // Workspace: el_ph[8N] | er_ph[8N] | rowptr[N+1] | (align) | feat_ph 8N*64B
    char* ws = (char*)d_ws;
    float* el_ph = (float*)ws;                    ws += (size_t)nh * 4;
    float* er_ph = (float*)ws;                    ws += (size_t)nh * 4;
    int* rowptr = (int*)ws;                       ws += (size_t)(n_nodes + 1) * 4;
    ws = (char*)(((uintptr_t)ws + 15) & ~(uintptr_t)15);
    uint2* feat_ph2 = (uint2*)ws;

    int nb_logits = (n_nodes + 3) / 4;            // 1 wave/node, 4 per block
    int nb_rowptr = (n_edges + 255) / 256;
    hipLaunchKernelGGL(gat_prep_kernel,
                       dim3(nb_logits + nb_rowptr), dim3(256), 0, stream,
                       (const float4*)feat, (const float4*)attn_l,
                       (const float4*)attn_r, el_ph, er_ph, feat_ph2,
                       dst, rowptr, n_nodes, n_edges, nb_logits);

    // 8 heads x ceil(N/4) node-groups; h = blockIdx & 7 (XCD partition)
    int blocks = 8 * ((n_nodes + 3) / 4);
    hipLaunchKernelGGL(gat_aggregate_kernel,
                       dim3(blocks), dim3(256), 0, stream,
                       (const unsigned int*)feat_ph2, el_ph, er_ph, src, rowptr,
                       (f32x2*)out, n_nodes);
}

// Round 12
// 133.992 us; speedup vs baseline: 1.3441x; 1.3441x over previous
//
#include <hip/hip_runtime.h>
#include <hip/hip_fp16.h>
#include <math.h>

#define HEADS 8
#define DIM 32
#define NEG_SLOPE 0.2f

typedef float f32x2 __attribute__((ext_vector_type(2)));
typedef float f32x4 __attribute__((ext_vector_type(4)));

__device__ inline float2 u2f2(unsigned int u) {
    __half2 h = __builtin_bit_cast(__half2, u);
    return __half22float2(h);
}
__device__ inline unsigned short f2bf(float f) {       // RNE f32 -> bf16
    unsigned int u = __builtin_bit_cast(unsigned int, f);
    u += 0x7FFFu + ((u >> 16) & 1u);
    return (unsigned short)(u >> 16);
}
__device__ inline float bf2f(unsigned short b) {
    unsigned int u = ((unsigned int)b) << 16;
    return __builtin_bit_cast(float, u);
}

// Prep (merged): blocks [0, nb_logits): one wave per node — logits el/er in
// [node][8] layout (for the edge kernel's float4 loads) and fp16 feat in
// per-head chunks feat_ph[h][node][32] (64B per (h,node), the XCD partition).
// Blocks [nb_logits, ...): CSR rowptr from sorted dst_idx (edge-parallel).
__global__ __launch_bounds__(256) void gat_prep_kernel(
    const float4* __restrict__ feat4,    // node row = 64 float4
    const float4* __restrict__ attn_l4,  // 64 float4 (8 heads x 8)
    const float4* __restrict__ attn_r4,
    float* __restrict__ el_n,            // [n_nodes][8]
    float* __restrict__ er_n,            // [n_nodes][8]
    uint2* __restrict__ feat_ph2,        // [8][n_nodes][8] uint2
    const int* __restrict__ dst,
    int* __restrict__ rowptr,
    int n_nodes, int n_edges, int nb_logits) {
    int b = blockIdx.x;
    if (b < nb_logits) {
        int wid = (b * 256 + threadIdx.x) >> 6;
        if (wid >= n_nodes) return;
        int lane = threadIdx.x & 63;
        int h = lane >> 3;
        int q = lane & 7;

        float4 al = attn_l4[lane];
        float4 ar = attn_r4[lane];
        float4 v  = feat4[(size_t)wid * 64 + lane];

        float sl = v.x * al.x + v.y * al.y + v.z * al.z + v.w * al.w;
        float sr = v.x * ar.x + v.y * ar.y + v.z * ar.z + v.w * ar.w;
#pragma unroll
        for (int off = 1; off < 8; off <<= 1) {
            sl += __shfl_xor(sl, off, 64);
            sr += __shfl_xor(sr, off, 64);
        }
        if (q == 0) {
            el_n[(unsigned)wid * 8 + h] = sl;
            er_n[(unsigned)wid * 8 + h] = sr;
        }
        unsigned hN = (unsigned)h * (unsigned)n_nodes;
        uint2 o;
        o.x = __builtin_bit_cast(unsigned int, __floats2half2_rn(v.x, v.y));
        o.y = __builtin_bit_cast(unsigned int, __floats2half2_rn(v.z, v.w));
        feat_ph2[((size_t)hN + (unsigned)wid) * 8 + q] = o;
    } else {
        int e = (b - nb_logits) * 256 + threadIdx.x;
        if (e >= n_edges) return;
        int d = dst[e];
        int prev = (e > 0) ? dst[e - 1] : -1;
        for (int v = prev + 1; v <= d; ++v) rowptr[v] = e;
        if (e == n_edges - 1) {
            for (int v = d + 1; v <= n_nodes; ++v) rowptr[v] = n_edges;
        }
    }
}

// Edge-weight kernel: one thread per edge computes all 8 heads' unnormalized
// softmax weights w = exp(lrelu(el[u]+er[v])) once, stored bf16 head-major
// w_ph[h][e] (sequential per segment -> streams). Removes el-gather + exp
// from the aggregate's hot loop (R10's 3.4x VALU regression).
__global__ __launch_bounds__(256) void gat_edgew_kernel(
    const float4* __restrict__ el_n4,    // [n_nodes][2] float4
    const float4* __restrict__ er_n4,
    const int* __restrict__ src_idx,
    const int* __restrict__ dst_idx,
    unsigned short* __restrict__ w_ph,   // [8][n_edges]
    int n_edges) {
    int e = blockIdx.x * blockDim.x + threadIdx.x;
    if (e >= n_edges) return;
    unsigned u = (unsigned)src_idx[e];
    unsigned v = (unsigned)dst_idx[e];
    float4 elA = el_n4[u * 2], elB = el_n4[u * 2 + 1];
    float4 erA = er_n4[v * 2], erB = er_n4[v * 2 + 1];
    float s[8];
    s[0] = elA.x + erA.x; s[1] = elA.y + erA.y;
    s[2] = elA.z + erA.z; s[3] = elA.w + erA.w;
    s[4] = elB.x + erB.x; s[5] = elB.y + erB.y;
    s[6] = elB.z + erB.z; s[7] = elB.w + erB.w;
#pragma unroll
    for (int h = 0; h < 8; ++h) {
        float t = fmaxf(s[h], NEG_SLOPE * s[h]);   // leaky relu
        w_ph[(size_t)h * (unsigned)n_edges + (unsigned)e] = f2bf(__expf(t));
    }
}

// Aggregate: head h = blockIdx.x & 7 -> all blocks of head h land on XCD h
// (round-robin dispatch), whose private L2 holds that head's 3.2 MB feat
// chunk (proven R10: FETCH 253->31.5 MB). Hot loop now only: src load ->
// fp16 feat uint2 gather + broadcast bf16 w + FMA. 8 edge-slots x 8 q-lanes,
// unroll x2 = 16 edges in flight. shfl_xor(8,16,32) cross-slot reduce.
__global__ __launch_bounds__(256) void gat_aggregate_kernel(
    const uint2* __restrict__ feat_ph2,        // [8][n_nodes][8] uint2
    const unsigned short* __restrict__ w_ph,   // [8][n_edges]
    const int* __restrict__ src_idx,
    const int* __restrict__ rowptr,
    f32x4* __restrict__ out4,                  // [n_nodes*64] float4
    int n_nodes, int n_edges) {
    int b = blockIdx.x;
    int h = b & 7;                      // XCD-partitioned head
    int vraw = (b >> 3) * 4 + (threadIdx.x >> 6);
    if (vraw >= n_nodes) return;
    int v = __builtin_amdgcn_readfirstlane(vraw);
    int lane = threadIdx.x & 63;
    int slot = lane >> 3;               // edge slot 0..7
    int q    = lane & 7;                // uint2 (4 dims) within 64B chunk

    int start = __builtin_amdgcn_readfirstlane(rowptr[v]);
    int end   = __builtin_amdgcn_readfirstlane(rowptr[v + 1]);

    unsigned ob = ((unsigned)v << 6) + ((unsigned)h << 3) + (unsigned)q;
    if (start == end) {
        if (slot == 0) {
            f32x4 z = {0.f, 0.f, 0.f, 0.f};
            __builtin_nontemporal_store(z, &out4[ob]);
        }
        return;
    }
    int endm1 = end - 1;
    unsigned hN = (unsigned)h * (unsigned)n_nodes;
    unsigned hE = (unsigned)h * (unsigned)n_edges;

    float den0 = 0.f, den1 = 0.f;
    f32x4 acc0 = {0.f, 0.f, 0.f, 0.f};
    f32x4 acc1 = {0.f, 0.f, 0.f, 0.f};

    for (int e0 = start; e0 < end; e0 += 16) {
        int eA = e0 + slot;
        int eB = e0 + 8 + slot;
        int eeA = eA < endm1 ? eA : endm1;
        int eeB = eB < endm1 ? eB : endm1;
        int uA = src_idx[eeA];
        int uB = src_idx[eeB];
        uint2 fA = feat_ph2[((size_t)hN + (unsigned)uA) * 8 + q];
        uint2 fB = feat_ph2[((size_t)hN + (unsigned)uB) * 8 + q];
        float wA = bf2f(w_ph[hE + (unsigned)eeA]);
        float wB = bf2f(w_ph[hE + (unsigned)eeB]);
        if (eA > endm1) wA = 0.f;
        if (eB > endm1) wB = 0.f;
        float2 a0 = u2f2(fA.x), a1 = u2f2(fA.y);
        float2 b0 = u2f2(fB.x), b1 = u2f2(fB.y);
        den0 += wA; den1 += wB;
        acc0.x += wA * a0.x; acc0.y += wA * a0.y;
        acc0.z += wA * a1.x; acc0.w += wA * a1.y;
        acc1.x += wB * b0.x; acc1.y += wB * b0.y;
        acc1.z += wB * b1.x; acc1.w += wB * b1.y;
    }
    f32x4 acc = acc0 + acc1;
    float den = den0 + den1;
#pragma unroll
    for (int off = 8; off < 64; off <<= 1) {
        acc.x += __shfl_xor(acc.x, off, 64);
        acc.y += __shfl_xor(acc.y, off, 64);
        acc.z += __shfl_xor(acc.z, off, 64);
        acc.w += __shfl_xor(acc.w, off, 64);
        den   += __shfl_xor(den,   off, 64);
    }
    if (slot == 0) {
        float inv = 1.f / den;
        f32x4 r = {acc.x * inv, acc.y * inv, acc.z * inv, acc.w * inv};
        __builtin_nontemporal_store(r, &out4[ob]);
    }
}

extern "C" void kernel_launch(void* const* d_in, const int* in_sizes, int n_in,
                              void* d_out, int out_size, void* d_ws, size_t ws_size,
                              hipStream_t stream) {
    const float* feat   = (const float*)d_in[0];
    const float* attn_l = (const float*)d_in[1];
    const float* attn_r = (const float*)d_in[2];
    const int*   src    = (const int*)d_in[3];
    const int*   dst    = (const int*)d_in[4];
    float* out = (float*)d_out;

    int n_edges = in_sizes[3];
    int n_nodes = out_size / (HEADS * DIM);
    int nh = n_nodes * HEADS;

    // Workspace: el_n[8N] f32 | er_n[8N] f32 | rowptr[N+1] | (align16)
    //            | feat_ph [8][N][32] fp16 = nh*64 BYTES | w_ph[8E] bf16
    char* ws = (char*)d_ws;
    float* el_n = (float*)ws;                     ws += (size_t)nh * 4;
    float* er_n = (float*)ws;                     ws += (size_t)nh * 4;
    int* rowptr = (int*)ws;                       ws += (size_t)(n_nodes + 1) * 4;
    ws = (char*)(((uintptr_t)ws + 15) & ~(uintptr_t)15);
    uint2* feat_ph2 = (uint2*)ws;                 ws += (size_t)nh * 64;   // FIXED (was nh*32)
    unsigned short* w_ph = (unsigned short*)ws;

    int nb_logits = (n_nodes + 3) / 4;            // 1 wave/node, 4 per block
    int nb_rowptr = (n_edges + 255) / 256;
    hipLaunchKernelGGL(gat_prep_kernel,
                       dim3(nb_logits + nb_rowptr), dim3(256), 0, stream,
                       (const float4*)feat, (const float4*)attn_l,
                       (const float4*)attn_r, el_n, er_n, feat_ph2,
                       dst, rowptr, n_nodes, n_edges, nb_logits);

    hipLaunchKernelGGL(gat_edgew_kernel,
                       dim3((n_edges + 255) / 256), dim3(256), 0, stream,
                       (const float4*)el_n, (const float4*)er_n, src, dst,
                       w_ph, n_edges);

    // 8 heads x ceil(N/4) node-groups; h = blockIdx & 7 (XCD partition)
    int blocks = 8 * ((n_nodes + 3) / 4);
    hipLaunchKernelGGL(gat_aggregate_kernel,
                       dim3(blocks), dim3(256), 0, stream,
                       feat_ph2, w_ph, src, rowptr, (f32x4*)out,
                       n_nodes, n_edges);
}